// Round 10
// baseline (172.770 us; speedup 1.0000x reference)
//
#include <hip/hip_runtime.h>
#include <math.h>

#define IMG_H 512
#define IMG_W 512
#define N_IMG 96            // 32 * 3
#define TW 32               // tile width (output cols)
#define TH 32               // tile height (output rows)
#define KS 11
#define IN_ROWS 42          // TH + 10
#define NUNITS (IN_ROWS * 8)    // 336 horizontal-conv units (4 px each)
#define STRIDE 33           // odd LDS row stride -> 2-way banks (free, measured 0)
#define PLANE (IN_ROWS * STRIDE)   // 1386
#define GRID 1536           // 96 images * 16 tile-rows = 6 blocks/CU exactly
#define TILES_X 16
#define TOTAL_N 25165824.0  // 32*3*512*512

// Round-10: PERSISTENT BLOCKS. Rounds 1-9 all showed OccupancyPercent pinned
// at ~34% (~2.9 blocks/CU) regardless of LDS size: with 24576 short blocks,
// resident = dispatch-rate x block-latency, i.e. workgroup churn starves the
// CUs and memory latency is never hidden (VALUBusy 64%).
// Fix: grid = 1536 (= 6 blocks/CU, the LDS residency limit). Block b owns
// image b/16, tile-row b%16 and loops tx=0..15 over its 512x32 strip.
//  - horizontal halos: L1-warm (same block just read them)
//  - vertical halos: blocks b+-16 -> same XCD (16 % 8 == 0) -> L2-warm
//  - only a scalar `acc` lives across tiles; block-reduce ONCE at the end.
// Stage internals identical to round 9 (measured: conflicts 0, no spill):
//  - u/v basis, 4 conv maps, gather-then-convolve, stride-33 LDS planes.

__global__ __launch_bounds__(256, 4) void ssim_tile_kernel(
    const float* __restrict__ pred, const float* __restrict__ targ,
    const float* __restrict__ k2d, float* __restrict__ partial)
{
    __shared__ float H[4][PLANE];
    __shared__ float wsum[4];

    const int tid = threadIdx.x;
    const int bid = blockIdx.x;
    const int img = bid >> 4;          // b / 16
    const int ty  = bid & 15;          // tile-row within image
    const int y0  = ty * TH;

    // exact 1D gaussian from the 2D kernel: k2d[5][j] = g5 * g[j], k2d[5][5] = g5^2
    float g[KS];
    {
        const float inv = rsqrtf(k2d[5 * KS + 5]);
        #pragma unroll
        for (int j = 0; j < KS; ++j) g[j] = k2d[5 * KS + j] * inv;
    }

    const float* __restrict__ Pimg = pred + (size_t)img * (IMG_H * IMG_W);
    const float* __restrict__ Timg = targ + (size_t)img * (IMG_H * IMG_W);

    const float C1 = 1.0e-4f;   // (0.01*1)^2
    const float C2 = 9.0e-4f;   // (0.03*1)^2
    float acc = 0.0f;           // per-thread SSIM sum across all 16 tiles

    for (int tx = 0; tx < TILES_X; ++tx) {
        const int x0 = tx * TW;

        // ---- stage 1: horizontal 11-tap pass on u,v,u^2,v^2 -> LDS planes ----
        #pragma unroll
        for (int b = 0; b < 2; ++b) {
            const int u = tid + (b << 8);
            if (u < NUNITS) {
                const int r    = u >> 3;           // 0..41
                const int cg   = u & 7;            // 0..7
                const int gr   = y0 - 5 + r;
                const int col0 = x0 + (cg << 2) - 8;   // 16B-aligned window start
                const bool rowok = ((unsigned)gr < (unsigned)IMG_H);
                const float* rowP = Pimg + (size_t)(rowok ? gr : 0) * IMG_W;
                const float* rowT = Timg + (size_t)(rowok ? gr : 0) * IMG_W;

                float p[20], t[20];
                if (rowok && col0 >= 0 && col0 + 20 <= IMG_W) {
                    #pragma unroll
                    for (int q = 0; q < 5; ++q) {
                        const float4 vp = *(const float4*)(rowP + col0 + 4 * q);
                        const float4 vt = *(const float4*)(rowT + col0 + 4 * q);
                        p[4*q+0] = vp.x; p[4*q+1] = vp.y; p[4*q+2] = vp.z; p[4*q+3] = vp.w;
                        t[4*q+0] = vt.x; t[4*q+1] = vt.y; t[4*q+2] = vt.z; t[4*q+3] = vt.w;
                    }
                } else {
                    #pragma unroll
                    for (int e = 0; e < 20; ++e) {
                        const int c  = col0 + e;
                        const int cc = min(max(c, 0), IMG_W - 1);
                        const bool ok = rowok && (c >= 0) && (c < IMG_W);
                        const float pv = rowP[cc];
                        const float tv = rowT[cc];
                        p[e] = ok ? pv : 0.0f;
                        t[e] = ok ? tv : 0.0f;
                    }
                }

                // transform to u,v in place over the used range (elems 3..17)
                #pragma unroll
                for (int i = 0; i < 15; ++i) {
                    const float pv = p[3 + i];
                    const float tv = t[3 + i];
                    p[3 + i] = pv + tv;     // u
                    t[3 + i] = pv - tv;     // v
                }

                // mu convs of u,v
                float au[4], av[4];
                #pragma unroll
                for (int k = 0; k < 4; ++k) { au[k] = 0.f; av[k] = 0.f; }
                #pragma unroll
                for (int k = 0; k < 4; ++k) {
                    #pragma unroll
                    for (int j = 0; j < KS; ++j) {
                        au[k] = fmaf(g[j], p[3 + k + j], au[k]);
                        av[k] = fmaf(g[j], t[3 + k + j], av[k]);
                    }
                }
                // square in place, then second-moment convs
                #pragma unroll
                for (int i = 0; i < 15; ++i) {
                    p[3 + i] *= p[3 + i];   // u^2
                    t[3 + i] *= t[3 + i];   // v^2
                }
                float auu[4], avv[4];
                #pragma unroll
                for (int k = 0; k < 4; ++k) { auu[k] = 0.f; avv[k] = 0.f; }
                #pragma unroll
                for (int k = 0; k < 4; ++k) {
                    #pragma unroll
                    for (int j = 0; j < KS; ++j) {
                        auu[k] = fmaf(g[j], p[3 + k + j], auu[k]);
                        avv[k] = fmaf(g[j], t[3 + k + j], avv[k]);
                    }
                }

                const int wb = r * STRIDE + (cg << 2);
                #pragma unroll
                for (int e = 0; e < 4; ++e) {
                    H[0][wb + e] = au[e];
                    H[1][wb + e] = av[e];
                    H[2][wb + e] = auu[e];
                    H[3][wb + e] = avv[e];
                }
            }
        }
        __syncthreads();

        // ---- stage 2: vertical 11-tap pass + SSIM formula ----
        {
            const int col  = tid & 31;
            const int rg   = tid >> 5;          // 0..7, rows rg*4 .. rg*4+3
            const int base = rg * 4 * STRIDE + col;

            float vu[14], vv[14], vuu[14], vvv[14];
            #pragma unroll
            for (int i = 0; i < 14; ++i) {
                const int idx = base + i * STRIDE;
                vu [i] = H[0][idx];
                vv [i] = H[1][idx];
                vuu[i] = H[2][idx];
                vvv[i] = H[3][idx];
            }

            #pragma unroll
            for (int k = 0; k < 4; ++k) {
                float au = 0.f, av = 0.f, auu = 0.f, avv = 0.f;
                #pragma unroll
                for (int j = 0; j < KS; ++j) {
                    au  = fmaf(g[j], vu [k + j], au);
                    av  = fmaf(g[j], vv [k + j], av);
                    auu = fmaf(g[j], vuu[k + j], auu);
                    avv = fmaf(g[j], vvv[k + j], avv);
                }
                const float u2 = au * au;        // muu^2
                const float v2 = av * av;        // muv^2
                const float A  = u2 - v2;        // 4*mux*muy
                const float B  = u2 + v2;        // 2*(mux^2+muy^2)
                const float Cd = auu - avv;      // 4*conv(xy)
                const float Cs = auu + avv;      // 2*(conv(x^2)+conv(y^2))
                const float num1 = fmaf(0.5f, A, C1);        // 2 mux muy + C1
                const float den1 = fmaf(0.5f, B, C1);        // mux^2+muy^2 + C1
                const float num2 = fmaf(0.5f, Cd - A, C2);   // 2 sigma_xy + C2
                const float den2 = fmaf(0.5f, Cs - B, C2);   // sx2+sy2 + C2
                acc = fmaf(num1 * num2, __builtin_amdgcn_rcpf(den1 * den2), acc);
            }
        }
        __syncthreads();   // protect H before next tile's stage 1
    }

    // ---- block reduction (once, after all 16 tiles) ----
    #pragma unroll
    for (int off = 32; off > 0; off >>= 1)
        acc += __shfl_down(acc, off, 64);

    const int lane = tid & 63;
    const int wid  = tid >> 6;
    if (lane == 0) wsum[wid] = acc;
    __syncthreads();
    if (tid == 0)
        partial[bid] = wsum[0] + wsum[1] + wsum[2] + wsum[3];
}

// ---------------- final reduction ----------------
__global__ __launch_bounds__(1024) void ssim_reduce_kernel(
    const float* __restrict__ partial, int n, float* __restrict__ out)
{
    const int tid = threadIdx.x;
    double s = 0.0;
    for (int i = tid; i < n; i += 1024) s += (double)partial[i];

    #pragma unroll
    for (int off = 32; off > 0; off >>= 1)
        s += __shfl_down(s, off, 64);

    __shared__ double dsum[16];
    const int lane = tid & 63;
    const int wid  = tid >> 6;
    if (lane == 0) dsum[wid] = s;
    __syncthreads();
    if (tid == 0) {
        double total = 0.0;
        #pragma unroll
        for (int w = 0; w < 16; ++w) total += dsum[w];
        out[0] = (float)(1.0 - total / TOTAL_N);
    }
}

extern "C" void kernel_launch(void* const* d_in, const int* in_sizes, int n_in,
                              void* d_out, int out_size, void* d_ws, size_t ws_size,
                              hipStream_t stream) {
    const float* pred = (const float*)d_in[0];
    const float* targ = (const float*)d_in[1];
    const float* k2d  = (const float*)d_in[2];
    float* out = (float*)d_out;
    float* ws  = (float*)d_ws;   // GRID partial sums

    ssim_tile_kernel<<<GRID, 256, 0, stream>>>(pred, targ, k2d, ws);
    ssim_reduce_kernel<<<1, 1024, 0, stream>>>(ws, GRID, out);
}

// Round 11
// 140.235 us; speedup vs baseline: 1.2320x; 1.2320x over previous
//
#include <hip/hip_runtime.h>
#include <math.h>

#define IMG_H 512
#define IMG_W 512
#define N_IMG 96            // 32 * 3
#define TW 32               // tile width (output cols)
#define TH 32               // tile height (output rows)
#define KS 11
#define IN_ROWS 42          // TH + 10
#define NUNITS (IN_ROWS * 8)    // 336 horizontal-conv units (4 px each)
#define STRIDE 33           // LDS row stride in float2 units
#define PLANE (IN_ROWS * STRIDE)   // 1386 float2
#define NBLOCKS (N_IMG * (IMG_W / TW) * (IMG_H / TH))   // 24576
#define TOTAL_N 25165824.0  // 32*3*512*512

// Round-11: occupancy attack. Evidence: r5 (5-map) and r9 (4-map, -24% VALU
// busy-time) hit the SAME 173 us wall at ~11 waves/CU -> latency-bound, not
// VALU-bound. r8 proved the CP follows the waves-per-EU request (occ 61%)
// but the tight VGPR budget spilled. So: request (256,5) AND cut true
// register pressure so the allocator survives:
//  - u,v formed per-chunk at load time; p/t never fully live (uw14+vw14)
//  - Gaussian symmetry: only g[0..5] kept, GW(j)=g6[min(j,10-j)] (static)
//  - stage 2 = streaming from LDS into 16 accumulators (no 56-float window;
//    LDS latency is short -- unlike r6's failed global-load streaming)
//  - LDS planes packed float2: Hu=(au,auu), Hv=(av,avv) -> ds instrs halved
// Math identical to r9 (absmax was 0.0).

#define GW(j) g6[(j) <= 5 ? (j) : 10 - (j)]

__global__ __launch_bounds__(256, 5) void ssim_tile_kernel(
    const float* __restrict__ pred, const float* __restrict__ targ,
    const float* __restrict__ k2d, float* __restrict__ partial)
{
    __shared__ float2 Hu[PLANE];
    __shared__ float2 Hv[PLANE];
    __shared__ float wsum[4];

    const int tid = threadIdx.x;
    const int bid = blockIdx.x;
    const int img = bid >> 8;          // 256 tiles per image
    const int tin = bid & 255;
    const int ty  = tin >> 4;          // 16 tiles per dim
    const int tx  = tin & 15;
    const int y0  = ty * TH;
    const int x0  = tx * TW;

    // exact 1D gaussian from the 2D kernel row 5: k2d[5][j] = g5*g[j]; symmetric
    float g6[6];
    {
        const float inv = rsqrtf(k2d[5 * KS + 5]);
        #pragma unroll
        for (int j = 0; j < 6; ++j) g6[j] = k2d[5 * KS + j] * inv;
    }

    const float* __restrict__ Pimg = pred + (size_t)img * (IMG_H * IMG_W);
    const float* __restrict__ Timg = targ + (size_t)img * (IMG_H * IMG_W);

    // ---- stage 1: horizontal 11-tap on u,v,u^2,v^2 -> packed LDS planes ----
    #pragma unroll
    for (int b = 0; b < 2; ++b) {
        const int u = tid + (b << 8);
        if (u < NUNITS) {
            const int r    = u >> 3;           // 0..41
            const int cg   = u & 7;            // 0..7
            const int gr   = y0 - 5 + r;
            const int col0 = x0 + (cg << 2) - 8;   // 16B-aligned window start
            const bool rowok = ((unsigned)gr < (unsigned)IMG_H);
            const float* rowP = Pimg + (size_t)(rowok ? gr : 0) * IMG_W;
            const float* rowT = Timg + (size_t)(rowok ? gr : 0) * IMG_W;

            // used window elems are 3..16 -> uw/vw[0..13]
            float uw[14], vw[14];
            if (rowok && col0 >= 0 && col0 + 20 <= IMG_W) {
                #pragma unroll
                for (int q = 0; q < 5; ++q) {
                    const float4 vp = *(const float4*)(rowP + col0 + 4 * q);
                    const float4 vt = *(const float4*)(rowT + col0 + 4 * q);
                    const float pe[4] = {vp.x, vp.y, vp.z, vp.w};
                    const float te[4] = {vt.x, vt.y, vt.z, vt.w};
                    #pragma unroll
                    for (int e = 0; e < 4; ++e) {
                        const int ge = 4 * q + e;          // compile-time
                        if (ge >= 3 && ge <= 16) {
                            uw[ge - 3] = pe[e] + te[e];
                            vw[ge - 3] = pe[e] - te[e];
                        }
                    }
                }
            } else {
                #pragma unroll
                for (int e = 3; e <= 16; ++e) {
                    const int c  = col0 + e;
                    const int cc = min(max(c, 0), IMG_W - 1);
                    const bool ok = rowok && (c >= 0) && (c < IMG_W);
                    const float pv = rowP[cc];
                    const float tv = rowT[cc];
                    uw[e - 3] = ok ? (pv + tv) : 0.0f;
                    vw[e - 3] = ok ? (pv - tv) : 0.0f;
                }
            }

            const int wb = r * STRIDE + (cg << 2);

            // u-maps: mu conv, square in place, second-moment conv, write
            {
                float au[4], auu[4];
                #pragma unroll
                for (int k = 0; k < 4; ++k) { au[k] = 0.f; }
                #pragma unroll
                for (int k = 0; k < 4; ++k) {
                    #pragma unroll
                    for (int j = 0; j < KS; ++j)
                        au[k] = fmaf(GW(j), uw[k + j], au[k]);
                }
                #pragma unroll
                for (int i = 0; i < 14; ++i) uw[i] *= uw[i];
                #pragma unroll
                for (int k = 0; k < 4; ++k) { auu[k] = 0.f; }
                #pragma unroll
                for (int k = 0; k < 4; ++k) {
                    #pragma unroll
                    for (int j = 0; j < KS; ++j)
                        auu[k] = fmaf(GW(j), uw[k + j], auu[k]);
                }
                #pragma unroll
                for (int e = 0; e < 4; ++e)
                    Hu[wb + e] = make_float2(au[e], auu[e]);
            }
            // v-maps
            {
                float av[4], avv[4];
                #pragma unroll
                for (int k = 0; k < 4; ++k) { av[k] = 0.f; }
                #pragma unroll
                for (int k = 0; k < 4; ++k) {
                    #pragma unroll
                    for (int j = 0; j < KS; ++j)
                        av[k] = fmaf(GW(j), vw[k + j], av[k]);
                }
                #pragma unroll
                for (int i = 0; i < 14; ++i) vw[i] *= vw[i];
                #pragma unroll
                for (int k = 0; k < 4; ++k) { avv[k] = 0.f; }
                #pragma unroll
                for (int k = 0; k < 4; ++k) {
                    #pragma unroll
                    for (int j = 0; j < KS; ++j)
                        avv[k] = fmaf(GW(j), vw[k + j], avv[k]);
                }
                #pragma unroll
                for (int e = 0; e < 4; ++e)
                    Hv[wb + e] = make_float2(av[e], avv[e]);
            }
        }
    }
    __syncthreads();

    // ---- stage 2: vertical 11-tap (streaming from LDS) + SSIM formula ----
    const int col = tid & 31;
    const int rg  = tid >> 5;          // 0..7, output rows rg*4 .. rg*4+3

    float sau[4], sav[4], sauu[4], savv[4];
    #pragma unroll
    for (int k = 0; k < 4; ++k) {
        sau[k] = 0.f; sav[k] = 0.f; sauu[k] = 0.f; savv[k] = 0.f;
    }

    #pragma unroll
    for (int i = 0; i < 14; ++i) {
        const int idx = (rg * 4 + i) * STRIDE + col;
        const float2 hu = Hu[idx];
        const float2 hv = Hv[idx];
        #pragma unroll
        for (int k = 0; k < 4; ++k) {
            const int j = i - k;                   // compile-time tap
            if (j >= 0 && j < KS) {
                sau [k] = fmaf(GW(j), hu.x, sau [k]);
                sauu[k] = fmaf(GW(j), hu.y, sauu[k]);
                sav [k] = fmaf(GW(j), hv.x, sav [k]);
                savv[k] = fmaf(GW(j), hv.y, savv[k]);
            }
        }
    }

    const float C1 = 1.0e-4f;   // (0.01*1)^2
    const float C2 = 9.0e-4f;   // (0.03*1)^2
    float lsum = 0.0f;
    #pragma unroll
    for (int k = 0; k < 4; ++k) {
        const float u2 = sau[k] * sau[k];   // muu^2
        const float v2 = sav[k] * sav[k];   // muv^2
        const float A  = u2 - v2;           // 4*mux*muy
        const float B  = u2 + v2;           // 2*(mux^2+muy^2)
        const float Cd = sauu[k] - savv[k]; // 4*conv(xy)
        const float Cs = sauu[k] + savv[k]; // 2*(conv(x^2)+conv(y^2))
        const float num1 = fmaf(0.5f, A, C1);        // 2 mux muy + C1
        const float den1 = fmaf(0.5f, B, C1);        // mux^2+muy^2 + C1
        const float num2 = fmaf(0.5f, Cd - A, C2);   // 2 sigma_xy + C2
        const float den2 = fmaf(0.5f, Cs - B, C2);   // sx2+sy2 + C2
        lsum = fmaf(num1 * num2, __builtin_amdgcn_rcpf(den1 * den2), lsum);
    }

    // ---- block reduction ----
    #pragma unroll
    for (int off = 32; off > 0; off >>= 1)
        lsum += __shfl_down(lsum, off, 64);

    const int lane = tid & 63;
    const int wid  = tid >> 6;
    if (lane == 0) wsum[wid] = lsum;
    __syncthreads();
    if (tid == 0)
        partial[bid] = wsum[0] + wsum[1] + wsum[2] + wsum[3];
}

// ---------------- final reduction ----------------
__global__ __launch_bounds__(1024) void ssim_reduce_kernel(
    const float* __restrict__ partial, int n, float* __restrict__ out)
{
    const int tid = threadIdx.x;
    double s = 0.0;
    for (int i = tid; i < n; i += 1024) s += (double)partial[i];

    #pragma unroll
    for (int off = 32; off > 0; off >>= 1)
        s += __shfl_down(s, off, 64);

    __shared__ double dsum[16];
    const int lane = tid & 63;
    const int wid  = tid >> 6;
    if (lane == 0) dsum[wid] = s;
    __syncthreads();
    if (tid == 0) {
        double total = 0.0;
        #pragma unroll
        for (int w = 0; w < 16; ++w) total += dsum[w];
        out[0] = (float)(1.0 - total / TOTAL_N);
    }
}

extern "C" void kernel_launch(void* const* d_in, const int* in_sizes, int n_in,
                              void* d_out, int out_size, void* d_ws, size_t ws_size,
                              hipStream_t stream) {
    const float* pred = (const float*)d_in[0];
    const float* targ = (const float*)d_in[1];
    const float* k2d  = (const float*)d_in[2];
    float* out = (float*)d_out;
    float* ws  = (float*)d_ws;   // NBLOCKS partial sums

    ssim_tile_kernel<<<NBLOCKS, 256, 0, stream>>>(pred, targ, k2d, ws);
    ssim_reduce_kernel<<<1, 1024, 0, stream>>>(ws, NBLOCKS, out);
}

// Round 12
// 139.969 us; speedup vs baseline: 1.2343x; 1.0019x over previous
//
#include <hip/hip_runtime.h>
#include <math.h>

#define IMG_H 512
#define IMG_W 512
#define N_IMG 96            // 32 * 3
#define TW 32               // tile width (output cols)
#define TH 32               // tile height (output rows)
#define KS 11
#define IN_ROWS 42          // TH + 10
#define NUNITS (IN_ROWS * 8)    // 336 horizontal-conv units (4 px each)
#define STRIDE 33           // LDS row stride in float2 units
#define PLANE (IN_ROWS * STRIDE)   // 1386 float2
#define NBLOCKS (N_IMG * (IMG_W / TW) * (IMG_H / TH))   // 24576
#define TOTAL_N 25165824.0  // 32*3*512*512

// Round-12: same kernel as round 11 (140 us, occ 54%, VGPR 36, no spill),
// with __launch_bounds__(256,7): LDS 22.2 KB allows 7 blocks/CU (155 KB),
// VGPR budget 512/7=73 is 2x the measured need (36) -> spill risk low.
// r11 proved the latency-bound theory: occupancy follows the waves/EU
// request; converting idle-latency cycles to issue cycles is the only
// remaining lever before the ~94 us VALU-issue floor.
//  - u,v formed per-chunk at load; p/t never fully live (uw14+vw14)
//  - Gaussian symmetry: g6[0..5], GW(j)=g6[min(j,10-j)] (static)
//  - stage 2 streams from LDS into 16 accumulators
//  - LDS planes packed float2: Hu=(au,auu), Hv=(av,avv)

#define GW(j) g6[(j) <= 5 ? (j) : 10 - (j)]

__global__ __launch_bounds__(256, 7) void ssim_tile_kernel(
    const float* __restrict__ pred, const float* __restrict__ targ,
    const float* __restrict__ k2d, float* __restrict__ partial)
{
    __shared__ float2 Hu[PLANE];
    __shared__ float2 Hv[PLANE];
    __shared__ float wsum[4];

    const int tid = threadIdx.x;
    const int bid = blockIdx.x;
    const int img = bid >> 8;          // 256 tiles per image
    const int tin = bid & 255;
    const int ty  = tin >> 4;          // 16 tiles per dim
    const int tx  = tin & 15;
    const int y0  = ty * TH;
    const int x0  = tx * TW;

    // exact 1D gaussian from the 2D kernel row 5: k2d[5][j] = g5*g[j]; symmetric
    float g6[6];
    {
        const float inv = rsqrtf(k2d[5 * KS + 5]);
        #pragma unroll
        for (int j = 0; j < 6; ++j) g6[j] = k2d[5 * KS + j] * inv;
    }

    const float* __restrict__ Pimg = pred + (size_t)img * (IMG_H * IMG_W);
    const float* __restrict__ Timg = targ + (size_t)img * (IMG_H * IMG_W);

    // ---- stage 1: horizontal 11-tap on u,v,u^2,v^2 -> packed LDS planes ----
    #pragma unroll
    for (int b = 0; b < 2; ++b) {
        const int u = tid + (b << 8);
        if (u < NUNITS) {
            const int r    = u >> 3;           // 0..41
            const int cg   = u & 7;            // 0..7
            const int gr   = y0 - 5 + r;
            const int col0 = x0 + (cg << 2) - 8;   // 16B-aligned window start
            const bool rowok = ((unsigned)gr < (unsigned)IMG_H);
            const float* rowP = Pimg + (size_t)(rowok ? gr : 0) * IMG_W;
            const float* rowT = Timg + (size_t)(rowok ? gr : 0) * IMG_W;

            // used window elems are 3..16 -> uw/vw[0..13]
            float uw[14], vw[14];
            if (rowok && col0 >= 0 && col0 + 20 <= IMG_W) {
                #pragma unroll
                for (int q = 0; q < 5; ++q) {
                    const float4 vp = *(const float4*)(rowP + col0 + 4 * q);
                    const float4 vt = *(const float4*)(rowT + col0 + 4 * q);
                    const float pe[4] = {vp.x, vp.y, vp.z, vp.w};
                    const float te[4] = {vt.x, vt.y, vt.z, vt.w};
                    #pragma unroll
                    for (int e = 0; e < 4; ++e) {
                        const int ge = 4 * q + e;          // compile-time
                        if (ge >= 3 && ge <= 16) {
                            uw[ge - 3] = pe[e] + te[e];
                            vw[ge - 3] = pe[e] - te[e];
                        }
                    }
                }
            } else {
                #pragma unroll
                for (int e = 3; e <= 16; ++e) {
                    const int c  = col0 + e;
                    const int cc = min(max(c, 0), IMG_W - 1);
                    const bool ok = rowok && (c >= 0) && (c < IMG_W);
                    const float pv = rowP[cc];
                    const float tv = rowT[cc];
                    uw[e - 3] = ok ? (pv + tv) : 0.0f;
                    vw[e - 3] = ok ? (pv - tv) : 0.0f;
                }
            }

            const int wb = r * STRIDE + (cg << 2);

            // u-maps: mu conv, square in place, second-moment conv, write
            {
                float au[4], auu[4];
                #pragma unroll
                for (int k = 0; k < 4; ++k) { au[k] = 0.f; }
                #pragma unroll
                for (int k = 0; k < 4; ++k) {
                    #pragma unroll
                    for (int j = 0; j < KS; ++j)
                        au[k] = fmaf(GW(j), uw[k + j], au[k]);
                }
                #pragma unroll
                for (int i = 0; i < 14; ++i) uw[i] *= uw[i];
                #pragma unroll
                for (int k = 0; k < 4; ++k) { auu[k] = 0.f; }
                #pragma unroll
                for (int k = 0; k < 4; ++k) {
                    #pragma unroll
                    for (int j = 0; j < KS; ++j)
                        auu[k] = fmaf(GW(j), uw[k + j], auu[k]);
                }
                #pragma unroll
                for (int e = 0; e < 4; ++e)
                    Hu[wb + e] = make_float2(au[e], auu[e]);
            }
            // v-maps
            {
                float av[4], avv[4];
                #pragma unroll
                for (int k = 0; k < 4; ++k) { av[k] = 0.f; }
                #pragma unroll
                for (int k = 0; k < 4; ++k) {
                    #pragma unroll
                    for (int j = 0; j < KS; ++j)
                        av[k] = fmaf(GW(j), vw[k + j], av[k]);
                }
                #pragma unroll
                for (int i = 0; i < 14; ++i) vw[i] *= vw[i];
                #pragma unroll
                for (int k = 0; k < 4; ++k) { avv[k] = 0.f; }
                #pragma unroll
                for (int k = 0; k < 4; ++k) {
                    #pragma unroll
                    for (int j = 0; j < KS; ++j)
                        avv[k] = fmaf(GW(j), vw[k + j], avv[k]);
                }
                #pragma unroll
                for (int e = 0; e < 4; ++e)
                    Hv[wb + e] = make_float2(av[e], avv[e]);
            }
        }
    }
    __syncthreads();

    // ---- stage 2: vertical 11-tap (streaming from LDS) + SSIM formula ----
    const int col = tid & 31;
    const int rg  = tid >> 5;          // 0..7, output rows rg*4 .. rg*4+3

    float sau[4], sav[4], sauu[4], savv[4];
    #pragma unroll
    for (int k = 0; k < 4; ++k) {
        sau[k] = 0.f; sav[k] = 0.f; sauu[k] = 0.f; savv[k] = 0.f;
    }

    #pragma unroll
    for (int i = 0; i < 14; ++i) {
        const int idx = (rg * 4 + i) * STRIDE + col;
        const float2 hu = Hu[idx];
        const float2 hv = Hv[idx];
        #pragma unroll
        for (int k = 0; k < 4; ++k) {
            const int j = i - k;                   // compile-time tap
            if (j >= 0 && j < KS) {
                sau [k] = fmaf(GW(j), hu.x, sau [k]);
                sauu[k] = fmaf(GW(j), hu.y, sauu[k]);
                sav [k] = fmaf(GW(j), hv.x, sav [k]);
                savv[k] = fmaf(GW(j), hv.y, savv[k]);
            }
        }
    }

    const float C1 = 1.0e-4f;   // (0.01*1)^2
    const float C2 = 9.0e-4f;   // (0.03*1)^2
    float lsum = 0.0f;
    #pragma unroll
    for (int k = 0; k < 4; ++k) {
        const float u2 = sau[k] * sau[k];   // muu^2
        const float v2 = sav[k] * sav[k];   // muv^2
        const float A  = u2 - v2;           // 4*mux*muy
        const float B  = u2 + v2;           // 2*(mux^2+muy^2)
        const float Cd = sauu[k] - savv[k]; // 4*conv(xy)
        const float Cs = sauu[k] + savv[k]; // 2*(conv(x^2)+conv(y^2))
        const float num1 = fmaf(0.5f, A, C1);        // 2 mux muy + C1
        const float den1 = fmaf(0.5f, B, C1);        // mux^2+muy^2 + C1
        const float num2 = fmaf(0.5f, Cd - A, C2);   // 2 sigma_xy + C2
        const float den2 = fmaf(0.5f, Cs - B, C2);   // sx2+sy2 + C2
        lsum = fmaf(num1 * num2, __builtin_amdgcn_rcpf(den1 * den2), lsum);
    }

    // ---- block reduction ----
    #pragma unroll
    for (int off = 32; off > 0; off >>= 1)
        lsum += __shfl_down(lsum, off, 64);

    const int lane = tid & 63;
    const int wid  = tid >> 6;
    if (lane == 0) wsum[wid] = lsum;
    __syncthreads();
    if (tid == 0)
        partial[bid] = wsum[0] + wsum[1] + wsum[2] + wsum[3];
}

// ---------------- final reduction ----------------
__global__ __launch_bounds__(1024) void ssim_reduce_kernel(
    const float* __restrict__ partial, int n, float* __restrict__ out)
{
    const int tid = threadIdx.x;
    double s = 0.0;
    for (int i = tid; i < n; i += 1024) s += (double)partial[i];

    #pragma unroll
    for (int off = 32; off > 0; off >>= 1)
        s += __shfl_down(s, off, 64);

    __shared__ double dsum[16];
    const int lane = tid & 63;
    const int wid  = tid >> 6;
    if (lane == 0) dsum[wid] = s;
    __syncthreads();
    if (tid == 0) {
        double total = 0.0;
        #pragma unroll
        for (int w = 0; w < 16; ++w) total += dsum[w];
        out[0] = (float)(1.0 - total / TOTAL_N);
    }
}

extern "C" void kernel_launch(void* const* d_in, const int* in_sizes, int n_in,
                              void* d_out, int out_size, void* d_ws, size_t ws_size,
                              hipStream_t stream) {
    const float* pred = (const float*)d_in[0];
    const float* targ = (const float*)d_in[1];
    const float* k2d  = (const float*)d_in[2];
    float* out = (float*)d_out;
    float* ws  = (float*)d_ws;   // NBLOCKS partial sums

    ssim_tile_kernel<<<NBLOCKS, 256, 0, stream>>>(pred, targ, k2d, ws);
    ssim_reduce_kernel<<<1, 1024, 0, stream>>>(ws, NBLOCKS, out);
}

// Round 14
// 137.785 us; speedup vs baseline: 1.2539x; 1.0159x over previous
//
#include <hip/hip_runtime.h>
#include <math.h>

#define IMG_H 512
#define IMG_W 512
#define N_IMG 96            // 32 * 3
#define TW 32               // tile width (output cols)
#define TH 64               // tile height (output rows)  [r13: was 32]
#define KS 11
#define IN_ROWS 74          // TH + 10
#define NUNITS (IN_ROWS * 8)    // 592 horizontal-conv units (4 px each)
#define STRIDE 33           // LDS row stride in float2 units
#define PLANE (IN_ROWS * STRIDE)   // 2442 float2
#define NBLOCKS (N_IMG * (IMG_W / TW) * (IMG_H / TH))   // 96*16*8 = 12288
#define TOTAL_N 25165824.0  // 32*3*512*512

// Round-13 (resubmit; infra failure last round): HALVE the workgroup count
// (TH 32->64, 24576->12288 dispatches).
// r12 evidence: w=7 request changed nothing (occ 54%, 140us) -> launch-bounds
// lever exhausted; 24576/140us = 175 WG/us suggests a CP dispatch-rate wall
// (resident = 175 * 6.3us / 256 = 4.3 blk/CU = measured). Also VALUBusy is
// ~2x overstated (gfx94x 4-cyc formula vs CDNA4 SIMD-32 2-cyc): true VALU
// ~34%, so the VALU floor is ~50us, not 100 -- churn/latency is the wall.
// This round: same lean kernel as r12, each block does a 32x64 tile:
//  - dispatches halved -> tests dispatch-bound hypothesis directly
//  - halo overhead (TH+10)/TH: 1.31 -> 1.16 (-12% stage-1 work)
//  - LDS 39KB -> 4 blocks/CU (16 waves), same residency as today
//  - stage 2 does two row-group passes (rg, rg+8), shape otherwise identical

#define GW(j) g6[(j) <= 5 ? (j) : 10 - (j)]

__global__ __launch_bounds__(256, 4) void ssim_tile_kernel(
    const float* __restrict__ pred, const float* __restrict__ targ,
    const float* __restrict__ k2d, float* __restrict__ partial)
{
    __shared__ float2 Hu[PLANE];
    __shared__ float2 Hv[PLANE];
    __shared__ float wsum[4];

    const int tid = threadIdx.x;
    const int bid = blockIdx.x;
    const int img = bid >> 7;          // 128 tiles per image
    const int tin = bid & 127;
    const int ty  = tin >> 4;          // 0..7
    const int tx  = tin & 15;          // 0..15
    const int y0  = ty * TH;
    const int x0  = tx * TW;

    // exact 1D gaussian from the 2D kernel row 5: k2d[5][j] = g5*g[j]; symmetric
    float g6[6];
    {
        const float inv = rsqrtf(k2d[5 * KS + 5]);
        #pragma unroll
        for (int j = 0; j < 6; ++j) g6[j] = k2d[5 * KS + j] * inv;
    }

    const float* __restrict__ Pimg = pred + (size_t)img * (IMG_H * IMG_W);
    const float* __restrict__ Timg = targ + (size_t)img * (IMG_H * IMG_W);

    // ---- stage 1: horizontal 11-tap on u,v,u^2,v^2 -> packed LDS planes ----
    #pragma unroll
    for (int b = 0; b < 3; ++b) {
        const int u = tid + (b << 8);
        if (u < NUNITS) {
            const int r    = u >> 3;           // 0..73
            const int cg   = u & 7;            // 0..7
            const int gr   = y0 - 5 + r;
            const int col0 = x0 + (cg << 2) - 8;   // 16B-aligned window start
            const bool rowok = ((unsigned)gr < (unsigned)IMG_H);
            const float* rowP = Pimg + (size_t)(rowok ? gr : 0) * IMG_W;
            const float* rowT = Timg + (size_t)(rowok ? gr : 0) * IMG_W;

            // used window elems are 3..16 -> uw/vw[0..13]
            float uw[14], vw[14];
            if (rowok && col0 >= 0 && col0 + 20 <= IMG_W) {
                #pragma unroll
                for (int q = 0; q < 5; ++q) {
                    const float4 vp = *(const float4*)(rowP + col0 + 4 * q);
                    const float4 vt = *(const float4*)(rowT + col0 + 4 * q);
                    const float pe[4] = {vp.x, vp.y, vp.z, vp.w};
                    const float te[4] = {vt.x, vt.y, vt.z, vt.w};
                    #pragma unroll
                    for (int e = 0; e < 4; ++e) {
                        const int ge = 4 * q + e;          // compile-time
                        if (ge >= 3 && ge <= 16) {
                            uw[ge - 3] = pe[e] + te[e];
                            vw[ge - 3] = pe[e] - te[e];
                        }
                    }
                }
            } else {
                #pragma unroll
                for (int e = 3; e <= 16; ++e) {
                    const int c  = col0 + e;
                    const int cc = min(max(c, 0), IMG_W - 1);
                    const bool ok = rowok && (c >= 0) && (c < IMG_W);
                    const float pv = rowP[cc];
                    const float tv = rowT[cc];
                    uw[e - 3] = ok ? (pv + tv) : 0.0f;
                    vw[e - 3] = ok ? (pv - tv) : 0.0f;
                }
            }

            const int wb = r * STRIDE + (cg << 2);

            // u-maps: mu conv, square in place, second-moment conv, write
            {
                float au[4], auu[4];
                #pragma unroll
                for (int k = 0; k < 4; ++k) { au[k] = 0.f; }
                #pragma unroll
                for (int k = 0; k < 4; ++k) {
                    #pragma unroll
                    for (int j = 0; j < KS; ++j)
                        au[k] = fmaf(GW(j), uw[k + j], au[k]);
                }
                #pragma unroll
                for (int i = 0; i < 14; ++i) uw[i] *= uw[i];
                #pragma unroll
                for (int k = 0; k < 4; ++k) { auu[k] = 0.f; }
                #pragma unroll
                for (int k = 0; k < 4; ++k) {
                    #pragma unroll
                    for (int j = 0; j < KS; ++j)
                        auu[k] = fmaf(GW(j), uw[k + j], auu[k]);
                }
                #pragma unroll
                for (int e = 0; e < 4; ++e)
                    Hu[wb + e] = make_float2(au[e], auu[e]);
            }
            // v-maps
            {
                float av[4], avv[4];
                #pragma unroll
                for (int k = 0; k < 4; ++k) { av[k] = 0.f; }
                #pragma unroll
                for (int k = 0; k < 4; ++k) {
                    #pragma unroll
                    for (int j = 0; j < KS; ++j)
                        av[k] = fmaf(GW(j), vw[k + j], av[k]);
                }
                #pragma unroll
                for (int i = 0; i < 14; ++i) vw[i] *= vw[i];
                #pragma unroll
                for (int k = 0; k < 4; ++k) { avv[k] = 0.f; }
                #pragma unroll
                for (int k = 0; k < 4; ++k) {
                    #pragma unroll
                    for (int j = 0; j < KS; ++j)
                        avv[k] = fmaf(GW(j), vw[k + j], avv[k]);
                }
                #pragma unroll
                for (int e = 0; e < 4; ++e)
                    Hv[wb + e] = make_float2(av[e], avv[e]);
            }
        }
    }
    __syncthreads();

    // ---- stage 2: vertical 11-tap (streaming from LDS) + SSIM formula ----
    const int col = tid & 31;
    const int rg0 = tid >> 5;          // 0..7

    const float C1 = 1.0e-4f;   // (0.01*1)^2
    const float C2 = 9.0e-4f;   // (0.03*1)^2
    float lsum = 0.0f;

    #pragma unroll
    for (int pass = 0; pass < 2; ++pass) {
        const int rg = rg0 + (pass << 3);   // 0..15, rows rg*4 .. rg*4+3

        float sau[4], sav[4], sauu[4], savv[4];
        #pragma unroll
        for (int k = 0; k < 4; ++k) {
            sau[k] = 0.f; sav[k] = 0.f; sauu[k] = 0.f; savv[k] = 0.f;
        }

        #pragma unroll
        for (int i = 0; i < 14; ++i) {
            const int idx = (rg * 4 + i) * STRIDE + col;
            const float2 hu = Hu[idx];
            const float2 hv = Hv[idx];
            #pragma unroll
            for (int k = 0; k < 4; ++k) {
                const int j = i - k;                   // compile-time tap
                if (j >= 0 && j < KS) {
                    sau [k] = fmaf(GW(j), hu.x, sau [k]);
                    sauu[k] = fmaf(GW(j), hu.y, sauu[k]);
                    sav [k] = fmaf(GW(j), hv.x, sav [k]);
                    savv[k] = fmaf(GW(j), hv.y, savv[k]);
                }
            }
        }

        #pragma unroll
        for (int k = 0; k < 4; ++k) {
            const float u2 = sau[k] * sau[k];   // muu^2
            const float v2 = sav[k] * sav[k];   // muv^2
            const float A  = u2 - v2;           // 4*mux*muy
            const float B  = u2 + v2;           // 2*(mux^2+muy^2)
            const float Cd = sauu[k] - savv[k]; // 4*conv(xy)
            const float Cs = sauu[k] + savv[k]; // 2*(conv(x^2)+conv(y^2))
            const float num1 = fmaf(0.5f, A, C1);        // 2 mux muy + C1
            const float den1 = fmaf(0.5f, B, C1);        // mux^2+muy^2 + C1
            const float num2 = fmaf(0.5f, Cd - A, C2);   // 2 sigma_xy + C2
            const float den2 = fmaf(0.5f, Cs - B, C2);   // sx2+sy2 + C2
            lsum = fmaf(num1 * num2, __builtin_amdgcn_rcpf(den1 * den2), lsum);
        }
    }

    // ---- block reduction ----
    #pragma unroll
    for (int off = 32; off > 0; off >>= 1)
        lsum += __shfl_down(lsum, off, 64);

    const int lane = tid & 63;
    const int wid  = tid >> 6;
    if (lane == 0) wsum[wid] = lsum;
    __syncthreads();
    if (tid == 0)
        partial[bid] = wsum[0] + wsum[1] + wsum[2] + wsum[3];
}

// ---------------- final reduction ----------------
__global__ __launch_bounds__(1024) void ssim_reduce_kernel(
    const float* __restrict__ partial, int n, float* __restrict__ out)
{
    const int tid = threadIdx.x;
    double s = 0.0;
    for (int i = tid; i < n; i += 1024) s += (double)partial[i];

    #pragma unroll
    for (int off = 32; off > 0; off >>= 1)
        s += __shfl_down(s, off, 64);

    __shared__ double dsum[16];
    const int lane = tid & 63;
    const int wid  = tid >> 6;
    if (lane == 0) dsum[wid] = s;
    __syncthreads();
    if (tid == 0) {
        double total = 0.0;
        #pragma unroll
        for (int w = 0; w < 16; ++w) total += dsum[w];
        out[0] = (float)(1.0 - total / TOTAL_N);
    }
}

extern "C" void kernel_launch(void* const* d_in, const int* in_sizes, int n_in,
                              void* d_out, int out_size, void* d_ws, size_t ws_size,
                              hipStream_t stream) {
    const float* pred = (const float*)d_in[0];
    const float* targ = (const float*)d_in[1];
    const float* k2d  = (const float*)d_in[2];
    float* out = (float*)d_out;
    float* ws  = (float*)d_ws;   // NBLOCKS partial sums

    ssim_tile_kernel<<<NBLOCKS, 256, 0, stream>>>(pred, targ, k2d, ws);
    ssim_reduce_kernel<<<1, 1024, 0, stream>>>(ws, NBLOCKS, out);
}